// Round 3
// baseline (4911.557 us; speedup 1.0000x reference)
//
#include <hip/hip_runtime.h>
#include <cstdint>

#define TT 2048
#define NH 15
#define WPB 12   // waves per block -> 3 waves per SIMD (stall coverage via TLP)

typedef _Float16 half8 __attribute__((ext_vector_type(8)));
typedef float f32x4 __attribute__((ext_vector_type(4)));
typedef int int4v __attribute__((ext_vector_type(4)));

#define EXP2(x) __builtin_amdgcn_exp2f(x)
#define RCP(x) __builtin_amdgcn_rcpf(x)
#define SIGM(x) (RCP(1.0f + EXP2((x) * -1.4426950408889634f)))
#define TANHF(x) (fmaf(-2.0f, RCP(1.0f + EXP2((x) * 2.8853900817779268f)), 1.0f))
#define BPERM(addr, v) __builtin_amdgcn_ds_bpermute((addr), (v))
#define PKRTZ_I(a, b) __builtin_bit_cast(int, __builtin_amdgcn_cvt_pkrtz((a), (b)))

// MFMA formulation, layer-wavefront staggered. ONE tile (16 batch elems) per
// wave (R2 showed 2 tiles/wave exceeds register budget -> compiler
// serializes). New in R3: 12 waves per block -> 3 waves resident per SIMD,
// so independent recurrences interleave and cover each other's dependency
// stalls (R1 ran 1 wave/SIMD: VALUBusy 44%, rest = uncovered stalls).
//
// Fragment maps (m89-verified): A[m=lane&15][k=(lane>>4)*8+j];
// B[k][n=lane&15], same k map; D col=lane&15, row=(lane>>4)*4+r.
// Interleaved-K layout: k = 8q+j with
//   j<4  -> "in"  unit u = 4q+j   (prev-cell h; cell1: u15 = x)
//   j>=4 -> "own" unit u = 4q+j-4 (own recurrent h; u15 = bias 1.0)
// -> B fragment is LANE-LOCAL (no ds_bpermute): dwords =
//   { pk(in0,in1), pk(in2,in3), pk(own0,own1), pk(own2,own3) }
// Pad unit 15 state provably stays 0 (zero A row -> z=0 -> c,h stay 0).
//
// Stagger: at START of iteration i: h1f=h1(i-1), h2f=h2(i-2), h3f=h3(i-3).
// Iter i computes cell1->h1(i), cell2->h2(i-1), cell3->h3(i-2); head reads
// pre-update h3f -> out(i-3). Warmup: bias gated to 0 for cell2 (i<1) /
// cell3 (i<2). Tail iters (i>=TT) compute garbage never stored.
__global__ __launch_bounds__(WPB * 64)
void lstm3_mfma(const float* __restrict__ input,
                const float* __restrict__ w_ih1, const float* __restrict__ w_hh1,
                const float* __restrict__ b_ih1, const float* __restrict__ b_hh1,
                const float* __restrict__ w_ih2, const float* __restrict__ w_hh2,
                const float* __restrict__ b_ih2, const float* __restrict__ b_hh2,
                const float* __restrict__ w_ih3, const float* __restrict__ w_hh3,
                const float* __restrict__ b_ih3, const float* __restrict__ b_hh3,
                const float* __restrict__ w_lin, const float* __restrict__ b_lin,
                float* __restrict__ out, int ntiles)
{
    const int wid = threadIdx.x >> 6;
    const int tile = blockIdx.x * WPB + wid;
    if (tile >= ntiles) return;          // no barriers anywhere: safe early-exit

    const int lane = threadIdx.x & 63;
    const int n = lane & 15;          // element (B-col) AND unit-row (A-m) index
    const int q = lane >> 4;          // quad
    const bool q3 = (q == 3);

    // ---- A fragments (static, f16, interleaved-K layout) ----
    half8 a1[4], a2[4], a3[4];
#pragma unroll
    for (int g = 0; g < 4; ++g) {
        half8 t1 = {}, t2 = {}, t3 = {};
#pragma unroll
        for (int j = 0; j < 8; ++j) {
            const int u = 4 * q + (j & 3);
            const bool isin = (j < 4);
            float v1 = 0.f, v2 = 0.f, v3 = 0.f;
            if (n < NH) {   // m = n; pad row m=15 stays zero
                const int r = g * NH + n;
                if (isin) {
                    v1 = (u < NH) ? w_hh1[r * NH + u] : w_ih1[r];   // u15 = x col
                    v2 = (u < NH) ? w_ih2[r * NH + u] : 0.f;
                    v3 = (u < NH) ? w_ih3[r * NH + u] : 0.f;
                } else {
                    v1 = (u < NH) ? 0.f               : (b_ih1[r] + b_hh1[r]);
                    v2 = (u < NH) ? w_hh2[r * NH + u] : (b_ih2[r] + b_hh2[r]);
                    v3 = (u < NH) ? w_hh3[r * NH + u] : (b_ih3[r] + b_hh3[r]);
                }
            }
            t1[j] = (_Float16)v1; t2[j] = (_Float16)v2; t3[j] = (_Float16)v3;
        }
        a1[g] = t1; a2[g] = t2; a3[g] = t3;
    }

    // head weights: partial dot over this lane's 4 units
    float wl[4];
#pragma unroll
    for (int r = 0; r < 4; ++r) {
        const int u = 4 * q + r;
        wl[r] = (u < NH) ? w_lin[u] : 0.f;
    }
    const float blv = b_lin[0];

    const f32x4 z4 = {0.f, 0.f, 0.f, 0.f};

    // ---- state: lane (q,n) holds units 4q+r of element n ----
    float h1f[4] = {0.f, 0.f, 0.f, 0.f}, c1f[4] = {0.f, 0.f, 0.f, 0.f};
    float h2f[4] = {0.f, 0.f, 0.f, 0.f}, c2f[4] = {0.f, 0.f, 0.f, 0.f};
    float h3f[4] = {0.f, 0.f, 0.f, 0.f}, c3f[4] = {0.f, 0.f, 0.f, 0.f};

    const float* xrow = input + (size_t)(tile * 16 + n) * TT;
    float* orow = out + (size_t)(tile * 16 + n) * TT;

#define CELL_UPDATE(A, Bf, HF, CF) { \
    f32x4 d0 = __builtin_amdgcn_mfma_f32_16x16x32_f16(A[0], (Bf), z4, 0, 0, 0); \
    f32x4 d1 = __builtin_amdgcn_mfma_f32_16x16x32_f16(A[1], (Bf), z4, 0, 0, 0); \
    f32x4 d2 = __builtin_amdgcn_mfma_f32_16x16x32_f16(A[2], (Bf), z4, 0, 0, 0); \
    f32x4 d3 = __builtin_amdgcn_mfma_f32_16x16x32_f16(A[3], (Bf), z4, 0, 0, 0); \
    _Pragma("unroll") \
    for (int r = 0; r < 4; ++r) { \
        const float iv = SIGM(d0[r]); \
        const float fv = SIGM(d1[r]); \
        const float gv = TANHF(d2[r]); \
        const float ov = SIGM(d3[r]); \
        CF[r] = fmaf(fv, CF[r], iv * gv); \
        HF[r] = ov * TANHF(CF[r]); \
    } }

    float xtile = xrow[q];            // x for t = t0..t0+3 lives in quads 0..3
    float xtile_n = xrow[4 + q];      // next tile prefetch
    // x(0) broadcast (phase 0): src lane = 0*16 + n
    float xv = __int_as_float(BPERM(n * 4, __float_as_int(xtile)));
    float ysel = 0.f;
    const int bcast_base = n * 4;

#pragma unroll 1
    for (int t0 = 0; t0 < TT + 4; t0 += 4) {     // i = t0+ph, runs to TT+3
#pragma unroll
        for (int ph = 0; ph < 4; ++ph) {
            // ---- head (independent): out(i-3) from pre-update h3f ----
            float p = fmaf(wl[0], h3f[0],
                      fmaf(wl[1], h3f[1],
                      fmaf(wl[2], h3f[2], wl[3] * h3f[3])));
            p += __shfl_xor(p, 16, 64);   // sum across quads (same column n)
            p += __shfl_xor(p, 32, 64);
            const int pho = (ph + 1) & 3; // = (i-3)&3
            ysel = (q == pho) ? (p + blv) : ysel;

            // ---- pipelined broadcast of x(i+1) (used next iteration) ----
            const float xsrc = (ph == 3) ? xtile_n : xtile;
            const float xv_n = __int_as_float(
                BPERM(((ph + 1) & 3) * 64 + bcast_base, __float_as_int(xsrc)));

            // ---- lane-local B fragments from pre-update state ----
            const int pA1 = PKRTZ_I(h1f[0], h1f[1]);
            const int pB1 = PKRTZ_I(h1f[2], h1f[3]);   // q3 high = pad = 0
            const int pA2 = PKRTZ_I(h2f[0], h2f[1]);
            const int pB2 = PKRTZ_I(h2f[2], h2f[3]);
            const int pA3 = PKRTZ_I(h3f[0], h3f[1]);
            const int pB3 = PKRTZ_I(h3f[2], h3f[3]);

            const float bias2v = (ph >= 1 || t0 > 0) ? 1.0f : 0.0f;
            const float bias3v = (ph >= 2 || t0 > 0) ? 1.0f : 0.0f;

            // cell1: in = h1_prev (+x at k=27), own = {bias at k=31}
            const int4v b1 = { pA1,
                               q3 ? PKRTZ_I(h1f[2], xv) : pB1,
                               0,
                               q3 ? 0x3C000000 : 0 };
            // cell2: in = h1(i-1), own = h2(i-2) (+bias at k=31)
            const int4v b2 = { pA1, pB1, pA2,
                               q3 ? PKRTZ_I(h2f[2], bias2v) : pB2 };
            // cell3: in = h2(i-2), own = h3(i-3) (+bias at k=31)
            const int4v b3 = { pA2, pB2, pA3,
                               q3 ? PKRTZ_I(h3f[2], bias3v) : pB3 };

            const half8 B1 = __builtin_bit_cast(half8, b1);
            const half8 B2 = __builtin_bit_cast(half8, b2);
            const half8 B3 = __builtin_bit_cast(half8, b3);

            // ---- three independent cell updates (interleave freely) ----
            CELL_UPDATE(a1, B1, h1f, c1f)
            CELL_UPDATE(a2, B2, h2f, c2f)
            CELL_UPDATE(a3, B3, h3f, c3f)

            xv = xv_n;

            if (ph == 2) {                 // all 4 ysel phases complete here
                if (t0 >= 4) orow[t0 - 4 + q] = ysel;
            }
        }
        // tile advance + prefetch (clamped reads are discarded garbage)
        xtile = xtile_n;
        const int tn = t0 + 8 + q;
        xtile_n = xrow[(tn < TT) ? tn : q];
    }
#undef CELL_UPDATE
}

extern "C" void kernel_launch(void* const* d_in, const int* in_sizes, int n_in,
                              void* d_out, int out_size, void* d_ws, size_t ws_size,
                              hipStream_t stream) {
    const float* input = (const float*)d_in[0];
    const float* w_ih1 = (const float*)d_in[1];
    const float* w_hh1 = (const float*)d_in[2];
    const float* b_ih1 = (const float*)d_in[3];
    const float* b_hh1 = (const float*)d_in[4];
    const float* w_ih2 = (const float*)d_in[5];
    const float* w_hh2 = (const float*)d_in[6];
    const float* b_ih2 = (const float*)d_in[7];
    const float* b_hh2 = (const float*)d_in[8];
    const float* w_ih3 = (const float*)d_in[9];
    const float* w_hh3 = (const float*)d_in[10];
    const float* b_ih3 = (const float*)d_in[11];
    const float* b_hh3 = (const float*)d_in[12];
    const float* w_lin = (const float*)d_in[13];
    const float* b_lin = (const float*)d_in[14];
    float* out = (float*)d_out;

    const int B = in_sizes[0] / TT;      // 8192
    const int ntiles = B / 16;           // 512 tiles of 16 elems
    const int blocks = (ntiles + WPB - 1) / WPB;   // 43 blocks x 12 waves

    lstm3_mfma<<<blocks, WPB * 64, 0, stream>>>(
        input, w_ih1, w_hh1, b_ih1, b_hh1,
        w_ih2, w_hh2, b_ih2, b_hh2,
        w_ih3, w_hh3, b_ih3, b_hh3,
        w_lin, b_lin, out, ntiles);
}

// Round 4
// 1248.705 us; speedup vs baseline: 3.9333x; 3.9333x over previous
//
#include <hip/hip_runtime.h>
#include <cstdint>

#define TT 2048
#define NH 15

typedef _Float16 half8 __attribute__((ext_vector_type(8)));
typedef float f32x4 __attribute__((ext_vector_type(4)));
typedef int int4v __attribute__((ext_vector_type(4)));

#define EXP2(x) __builtin_amdgcn_exp2f(x)
#define RCP(x) __builtin_amdgcn_rcpf(x)
#define SIGM(x) (RCP(1.0f + EXP2((x) * -1.4426950408889634f)))
#define TANHF(x) (fmaf(-2.0f, RCP(1.0f + EXP2((x) * 2.8853900817779268f)), 1.0f))
#define BPERM(addr, v) __builtin_amdgcn_ds_bpermute((addr), (v))
#define PKRTZ_I(a, b) __builtin_bit_cast(int, __builtin_amdgcn_cvt_pkrtz((a), (b)))
#define MFMA16(A, B, C) __builtin_amdgcn_mfma_f32_16x16x32_f16((A), (B), (C), 0, 0, 0)

#define GATES(d0, d1, d2, d3, cref, hout) { \
    const float iv_ = SIGM(d0); \
    const float fv_ = SIGM(d1); \
    const float gv_ = TANHF(d2); \
    const float ov_ = SIGM(d3); \
    (cref) = fmaf(fv_, (cref), iv_ * gv_); \
    (hout) = ov_ * TANHF(cref); }

// raw barrier: LDS-ordering only (no vmcnt drain of x-prefetch / out-stores)
#define LDS_BAR() { asm volatile("s_waitcnt lgkmcnt(0)" ::: "memory"); \
                    __builtin_amdgcn_s_barrier(); }

// 2-wave cell-split, layer-wavefront staggered MFMA LSTM.
// Block = 128 threads = 2 waves, one 16-element batch tile.
//   wave A: cell1 (full) + cell3 gate-rows r=0,1
//   wave B: cell2 (full) + cell3 gate-rows r=2,3 + linear head (as MFMA)
// -> 1024 waves total = 1 wave/SIMD on ALL 1024 SIMDs (R1 used only 512),
// per-wave issue halves (~700 cy/step). MFMA pipe idle -> duplicating
// cell3's 4 MFMAs in both waves is free; only its VALU gate work is split.
//
// Fragment maps (m89-verified): A[m=lane&15][k=(lane>>4)*8+j];
// B[k][n=lane&15]; D col=lane&15, row=(lane>>4)*4+r.
// Interleaved-K layout: k=8q+j: j<4 -> "in" unit 4q+j (cell1: u15=x),
// j>=4 -> "own" unit 4q+j-4 (u15 = bias 1.0). B-fragment dwords are
// lane-local packed f16 pairs -> the values exchanged via LDS ARE the
// fragment words (producer packs once, both waves consume).
//
// Stagger at iter i: A computes h1(i), h3(i-2)[r01]; B computes h2(i-1),
// h3(i-2)[r23], y(i-3). Cross-wave data (all lag-1, one barrier/iter,
// parity double-buffer):  A->B: pk(h1(i)) x2, pk(h3(i-2)[0,1]);
// B->A: pk(h2(i-1)) x2, pk(h3(i-2)[2], ...q3 bias variant).
// Warmup: LDS + kept regs zero-init => all-zero fragments => sigma(0)*0
// keeps states exactly 0 for tau<0; only cell3's bias slot needs gating
// (produced-at-iter-0 word must carry bias=0), handled by g3 at ph==0.
// Tail iters (i>=TT) compute finite garbage never stored.
__global__ __launch_bounds__(128) __attribute__((amdgpu_waves_per_eu(1, 1)))
void lstm3_split(const float* __restrict__ input,
                 const float* __restrict__ w_ih1, const float* __restrict__ w_hh1,
                 const float* __restrict__ b_ih1, const float* __restrict__ b_hh1,
                 const float* __restrict__ w_ih2, const float* __restrict__ w_hh2,
                 const float* __restrict__ b_ih2, const float* __restrict__ b_hh2,
                 const float* __restrict__ w_ih3, const float* __restrict__ w_hh3,
                 const float* __restrict__ b_ih3, const float* __restrict__ b_hh3,
                 const float* __restrict__ w_lin, const float* __restrict__ b_lin,
                 float* __restrict__ out)
{
    // [parity][wave][slot][lane] dwords; slot-major -> lane-contiguous,
    // bank-conflict-free b32 accesses. 3 KiB.
    __shared__ int lds[2][2][3][64];

    const int tid = threadIdx.x;
    const int w = tid >> 6;           // 0 = wave A, 1 = wave B
    const int lane = tid & 63;
    const int n = lane & 15;          // element col AND A-row m
    const int q = lane >> 4;          // quad
    const bool q3 = (q == 3);

    // zero-init LDS (this IS the warmup state: zero fragments)
    for (int k = tid; k < 2 * 2 * 3 * 64; k += 128) ((int*)lds)[k] = 0;
    __syncthreads();

    const f32x4 z4 = {0.f, 0.f, 0.f, 0.f};

    if (w == 0) {
        // ================= wave A: cell1 + cell3[r01] =================
        half8 a1[4], a3[4];
#pragma unroll
        for (int g = 0; g < 4; ++g) {
            half8 t1 = {}, t3 = {};
#pragma unroll
            for (int j = 0; j < 8; ++j) {
                const int u = 4 * q + (j & 3);
                const bool isin = (j < 4);
                float v1 = 0.f, v3 = 0.f;
                if (n < NH) {
                    const int r = g * NH + n;
                    if (isin) {
                        v1 = (u < NH) ? w_hh1[r * NH + u] : w_ih1[r];
                        v3 = (u < NH) ? w_ih3[r * NH + u] : 0.f;
                    } else {
                        v1 = (u < NH) ? 0.f : (b_ih1[r] + b_hh1[r]);
                        v3 = (u < NH) ? w_hh3[r * NH + u] : (b_ih3[r] + b_hh3[r]);
                    }
                }
                t1[j] = (_Float16)v1; t3[j] = (_Float16)v3;
            }
            a1[g] = t1; a3[g] = t3;
        }

        float h1f[4] = {0.f, 0.f, 0.f, 0.f}, c1f[4] = {0.f, 0.f, 0.f, 0.f};
        float c3a0 = 0.f, c3a1 = 0.f;
        int pA3k = 0;                     // kept pk(h3[0],h3[1]) of last iter

        const float* xrow = input + (size_t)(blockIdx.x * 16 + n) * TT;
        float xtile = xrow[q];
        float xtile_n = xrow[4 + q];
        float xv = __int_as_float(BPERM(n * 4, __float_as_int(xtile)));

#pragma unroll 1
        for (int t0 = 0; t0 < TT + 4; t0 += 4) {
#pragma unroll
            for (int ph = 0; ph < 4; ++ph) {
                const int p = (t0 + ph) & 1, pr = p ^ 1;
                // ---- read B's packs (written last iter) ----
                const int rA2 = lds[pr][1][0][lane];
                const int rB2 = lds[pr][1][1][lane];
                const int rB3 = lds[pr][1][2][lane];
                // ---- x broadcast for next iter ----
                const float xsrc = (ph == 3) ? xtile_n : xtile;
                const float xv_n = __int_as_float(
                    BPERM(((ph + 1) & 3) * 64 + n * 4, __float_as_int(xsrc)));
                // ---- fragments ----
                const int pA1 = PKRTZ_I(h1f[0], h1f[1]);
                const int pB1 = PKRTZ_I(h1f[2], h1f[3]);
                const int4v b1 = { pA1,
                                   q3 ? PKRTZ_I(h1f[2], xv) : pB1,
                                   0,
                                   q3 ? 0x3C000000 : 0 };
                const int4v b3 = { rA2, rB2, pA3k, rB3 };
                const half8 B1 = __builtin_bit_cast(half8, b1);
                const half8 B3 = __builtin_bit_cast(half8, b3);
                // ---- MFMAs ----
                f32x4 D10 = MFMA16(a1[0], B1, z4);
                f32x4 D11 = MFMA16(a1[1], B1, z4);
                f32x4 D12 = MFMA16(a1[2], B1, z4);
                f32x4 D13 = MFMA16(a1[3], B1, z4);
                f32x4 D30 = MFMA16(a3[0], B3, z4);
                f32x4 D31 = MFMA16(a3[1], B3, z4);
                f32x4 D32 = MFMA16(a3[2], B3, z4);
                f32x4 D33 = MFMA16(a3[3], B3, z4);
                // ---- gates: cell1 r0..3 ----
                GATES(D10[0], D11[0], D12[0], D13[0], c1f[0], h1f[0]);
                GATES(D10[1], D11[1], D12[1], D13[1], c1f[1], h1f[1]);
                GATES(D10[2], D11[2], D12[2], D13[2], c1f[2], h1f[2]);
                GATES(D10[3], D11[3], D12[3], D13[3], c1f[3], h1f[3]);
                // ---- gates: cell3 r0,1 ----
                float h3a0, h3a1;
                GATES(D30[0], D31[0], D32[0], D33[0], c3a0, h3a0);
                GATES(D30[1], D31[1], D32[1], D33[1], c3a1, h3a1);
                // ---- producer packs + write ----
                const int wA1 = PKRTZ_I(h1f[0], h1f[1]);
                const int wB1 = PKRTZ_I(h1f[2], h1f[3]);
                const int wA3 = PKRTZ_I(h3a0, h3a1);
                lds[p][0][0][lane] = wA1;
                lds[p][0][1][lane] = wB1;
                lds[p][0][2][lane] = wA3;
                pA3k = wA3;
                xv = xv_n;
                LDS_BAR();
            }
            xtile = xtile_n;
            const int tn = t0 + 8 + q;
            xtile_n = xrow[(tn < TT) ? tn : q];
        }
    } else {
        // ============ wave B: cell2 + cell3[r23] + head ============
        half8 a2[4], a3[4];
#pragma unroll
        for (int g = 0; g < 4; ++g) {
            half8 t2 = {}, t3 = {};
#pragma unroll
            for (int j = 0; j < 8; ++j) {
                const int u = 4 * q + (j & 3);
                const bool isin = (j < 4);
                float v2 = 0.f, v3 = 0.f;
                if (n < NH) {
                    const int r = g * NH + n;
                    if (isin) {
                        v2 = (u < NH) ? w_ih2[r * NH + u] : 0.f;
                        v3 = (u < NH) ? w_ih3[r * NH + u] : 0.f;
                    } else {
                        v2 = (u < NH) ? w_hh2[r * NH + u] : (b_ih2[r] + b_hh2[r]);
                        v3 = (u < NH) ? w_hh3[r * NH + u] : (b_ih3[r] + b_hh3[r]);
                    }
                }
                t2[j] = (_Float16)v2; t3[j] = (_Float16)v3;
            }
            a2[g] = t2; a3[g] = t3;
        }
        // head A-fragment: row m=0 = w_lin over own-slots, b_lin at k=31
        half8 ah = {};
        if (n == 0) {
#pragma unroll
            for (int j = 4; j < 8; ++j) {
                const int u = 4 * q + (j - 4);
                ah[j] = (_Float16)((u < NH) ? w_lin[u] : b_lin[0]);
            }
        }

        float c2f[4] = {0.f, 0.f, 0.f, 0.f};
        float c3b2 = 0.f, c3b3 = 0.f;
        int pA2k = 0, pB2k = 0;   // kept raw pk(h2) (cell2-own + cell3-in)
        int ov2k = 0;             // kept q3 bias variant for cell2 own-word1
        int ov3k = 0;             // kept q3 bias variant for cell3 own-word1
        float y4[4] = {0.f, 0.f, 0.f, 0.f};

        float* orow = out + (size_t)(blockIdx.x * 16 + n) * TT;

#pragma unroll 1
        for (int t0 = 0; t0 < TT + 4; t0 += 4) {
#pragma unroll
            for (int ph = 0; ph < 4; ++ph) {
                const int p = (t0 + ph) & 1, pr = p ^ 1;
                // ---- read A's packs (written last iter) ----
                const int rA1 = lds[pr][0][0][lane];
                const int rB1 = lds[pr][0][1][lane];
                const int rA3 = lds[pr][0][2][lane];
                // ---- fragments ----
                const int4v b2 = { rA1, rB1, pA2k, ov2k };
                const int4v b3 = { pA2k, pB2k, rA3, ov3k };
                const half8 B2 = __builtin_bit_cast(half8, b2);
                const half8 B3 = __builtin_bit_cast(half8, b3);
                // ---- MFMAs ----
                f32x4 D20 = MFMA16(a2[0], B2, z4);
                f32x4 D21 = MFMA16(a2[1], B2, z4);
                f32x4 D22 = MFMA16(a2[2], B2, z4);
                f32x4 D23 = MFMA16(a2[3], B2, z4);
                f32x4 D30 = MFMA16(a3[0], B3, z4);
                f32x4 D31 = MFMA16(a3[1], B3, z4);
                f32x4 D32 = MFMA16(a3[2], B3, z4);
                f32x4 D33 = MFMA16(a3[3], B3, z4);
                f32x4 Dh  = MFMA16(ah,    B3, z4);     // y(i-3) in q0/r0
                // ---- gates: cell2 r0..3 ----
                float h2n0, h2n1, h2n2, h2n3;
                GATES(D20[0], D21[0], D22[0], D23[0], c2f[0], h2n0);
                GATES(D20[1], D21[1], D22[1], D23[1], c2f[1], h2n1);
                GATES(D20[2], D21[2], D22[2], D23[2], c2f[2], h2n2);
                GATES(D20[3], D21[3], D22[3], D23[3], c2f[3], h2n3);
                // ---- gates: cell3 r2,3 ----
                float h3b2, h3b3;
                GATES(D30[2], D31[2], D32[2], D33[2], c3b2, h3b2);
                GATES(D30[3], D31[3], D32[3], D33[3], c3b3, h3b3);
                // ---- head collect / store ----
                y4[(ph + 1) & 3] = Dh[0];
                if (ph == 2 && t0 >= 4 && q == 0) {
                    *(f32x4*)(orow + t0 - 4) =
                        (f32x4){y4[0], y4[1], y4[2], y4[3]};
                }
                // ---- producer packs + write ----
                const int wA2 = PKRTZ_I(h2n0, h2n1);
                const int wB2 = PKRTZ_I(h2n2, h2n3);
                const int nv2 = q3 ? PKRTZ_I(h2n2, 1.0f) : wB2;
                // bias for cell3 consumption next iter: tau = (i+1)-2 >= 0
                const float g3 = (ph >= 1 || t0 > 0) ? 1.0f : 0.0f;
                const int wB3 = q3 ? PKRTZ_I(h3b2, g3) : PKRTZ_I(h3b2, h3b3);
                lds[p][1][0][lane] = wA2;
                lds[p][1][1][lane] = wB2;
                lds[p][1][2][lane] = wB3;
                pA2k = wA2; pB2k = wB2; ov2k = nv2; ov3k = wB3;
                LDS_BAR();
            }
        }
    }
}

extern "C" void kernel_launch(void* const* d_in, const int* in_sizes, int n_in,
                              void* d_out, int out_size, void* d_ws, size_t ws_size,
                              hipStream_t stream) {
    const float* input = (const float*)d_in[0];
    const float* w_ih1 = (const float*)d_in[1];
    const float* w_hh1 = (const float*)d_in[2];
    const float* b_ih1 = (const float*)d_in[3];
    const float* b_hh1 = (const float*)d_in[4];
    const float* w_ih2 = (const float*)d_in[5];
    const float* w_hh2 = (const float*)d_in[6];
    const float* b_ih2 = (const float*)d_in[7];
    const float* b_hh2 = (const float*)d_in[8];
    const float* w_ih3 = (const float*)d_in[9];
    const float* w_hh3 = (const float*)d_in[10];
    const float* b_ih3 = (const float*)d_in[11];
    const float* b_hh3 = (const float*)d_in[12];
    const float* w_lin = (const float*)d_in[13];
    const float* b_lin = (const float*)d_in[14];
    float* out = (float*)d_out;

    const int B = in_sizes[0] / TT;      // 8192
    const int blocks = B / 16;           // 512 blocks x 2 waves = 1024 waves

    lstm3_split<<<blocks, 128, 0, stream>>>(
        input, w_ih1, w_hh1, b_ih1, b_hh1,
        w_ih2, w_hh2, b_ih2, b_hh2,
        w_ih3, w_hh3, b_ih3, b_hh3,
        w_lin, b_lin, out);
}